// Round 2
// baseline (472.337 us; speedup 1.0000x reference)
//
#include <hip/hip_runtime.h>

#define D 80
#define NE 1024

// ws layout:
//   [0,   8)                 : double loss accumulator (memset to 0 each call)
//   [64,  64+NE*D*4)         : normalized embed table en[NE][D]
//   [+..., +...+NE*4)        : ec[NE] = ||en_j||^2 (np sequential-k order)
//
// Bit-exact fp32 replication of the numpy reference:
//  - squares are rounded before summation (__fmul_rn then __fadd_rn; no FMA contraction)
//  - ||x||^2 uses numpy's pairwise 8-accumulator pattern (contiguous axis-1 sum, n=80)
//  - norms & ||e||^2 use sequential k-order adds (numpy axis-0 reduce is sequential)
//  - dot uses a sequential-k fp32 FMA chain (OpenBLAS sgemm micro-kernel order)
//  - dist = fl(fl(A - 2B) + C); argmin with strict < keeps first index on rounded ties

__global__ __launch_bounds__(256) void vq_prep(const float* __restrict__ w,
                                               float* __restrict__ en,
                                               float* __restrict__ ec) {
    int j = blockIdx.x * blockDim.x + threadIdx.x;
    if (j >= NE) return;
    const float* wj = w + j * D;
    // norm^2 = sequential sum over k of fl(w_k^2)   (np add.reduce over axis 0)
    float s = __fmul_rn(wj[0], wj[0]);
    for (int k = 1; k < D; ++k) s = __fadd_rn(s, __fmul_rn(wj[k], wj[k]));
    float norm = __fsqrt_rn(s);
    float* ej = en + j * D;
    float c = __fmul_rn(__fdiv_rn(wj[0], norm), __fdiv_rn(wj[0], norm));
    ej[0] = __fdiv_rn(wj[0], norm);
    for (int k = 1; k < D; ++k) {
        float v = __fdiv_rn(wj[k], norm);
        ej[k] = v;
        c = __fadd_rn(c, __fmul_rn(v, v));
    }
    ec[j] = c;
}

__global__ __launch_bounds__(256) void vq_main(
        const float* __restrict__ x,    // [n, D]
        const float* __restrict__ w,    // [NE, D] unnormalized
        const float* __restrict__ en,   // [NE, D] normalized
        const float* __restrict__ ec,   // [NE]
        float* __restrict__ out,        // [n, D]
        double* __restrict__ loss_acc,
        int n) {
    int r = blockIdx.x * blockDim.x + threadIdx.x;
    double ss = 0.0;
    if (r < n) {
        float X[D];
        const float4* x4 = (const float4*)(x + (size_t)r * D);
#pragma unroll
        for (int i = 0; i < D / 4; ++i) {
            float4 v = x4[i];
            X[4 * i + 0] = v.x; X[4 * i + 1] = v.y;
            X[4 * i + 2] = v.z; X[4 * i + 3] = v.w;
        }

        // A = ||x||^2 via numpy pairwise 8-accumulator pattern (n=80, no tail)
        float pr[8];
#pragma unroll
        for (int t = 0; t < 8; ++t) pr[t] = __fmul_rn(X[t], X[t]);
#pragma unroll
        for (int base = 8; base < D; base += 8) {
#pragma unroll
            for (int t = 0; t < 8; ++t)
                pr[t] = __fadd_rn(pr[t], __fmul_rn(X[base + t], X[base + t]));
        }
        float A = __fadd_rn(
            __fadd_rn(__fadd_rn(pr[0], pr[1]), __fadd_rn(pr[2], pr[3])),
            __fadd_rn(__fadd_rn(pr[4], pr[5]), __fadd_rn(pr[6], pr[7])));

        float best = 3.4e38f;
        int bi = 0;
        for (int j = 0; j < NE; ++j) {
            const float* ej = en + j * D;   // uniform address -> scalar loads
            float d = 0.f;
#pragma unroll
            for (int k = 0; k < D; ++k) d = __builtin_fmaf(X[k], ej[k], d);
            // dist = fl(fl(A - 2*d) + C_j)
            float score = __fadd_rn(__fsub_rn(A, __fmul_rn(2.0f, d)), ec[j]);
            if (score < best) { best = score; bi = j; }  // first index on ties
        }

        // gather unnormalized row; straight-through out = fl(x + fl(q - x))
        const float* wj = w + bi * D;
        float4* o4 = (float4*)(out + (size_t)r * D);
#pragma unroll
        for (int i = 0; i < D / 4; ++i) {
            float q0 = wj[4 * i + 0], q1 = wj[4 * i + 1];
            float q2 = wj[4 * i + 2], q3 = wj[4 * i + 3];
            float d0 = __fsub_rn(q0, X[4 * i + 0]);
            float d1 = __fsub_rn(q1, X[4 * i + 1]);
            float d2 = __fsub_rn(q2, X[4 * i + 2]);
            float d3 = __fsub_rn(q3, X[4 * i + 3]);
            float4 o;
            o.x = __fadd_rn(X[4 * i + 0], d0);
            o.y = __fadd_rn(X[4 * i + 1], d1);
            o.z = __fadd_rn(X[4 * i + 2], d2);
            o.w = __fadd_rn(X[4 * i + 3], d3);
            o4[i] = o;
            ss += (double)__fmul_rn(d0, d0) + (double)__fmul_rn(d1, d1);
            ss += (double)__fmul_rn(d2, d2) + (double)__fmul_rn(d3, d3);
        }
    }

    // wave64 reduce -> block reduce -> one f64 atomic per block
#pragma unroll
    for (int off = 32; off > 0; off >>= 1) ss += __shfl_down(ss, off);
    __shared__ double bsum[4];
    int wid = threadIdx.x >> 6;
    if ((threadIdx.x & 63) == 0) bsum[wid] = ss;
    __syncthreads();
    if (threadIdx.x == 0) {
        atomicAdd(loss_acc, bsum[0] + bsum[1] + bsum[2] + bsum[3]);
    }
}

__global__ void vq_fin_kernel(const double* __restrict__ acc,
                              float* __restrict__ out_loss,
                              double count) {
    float m = (float)(*acc / count);                       // mean((q-x)^2)
    *out_loss = __fadd_rn(m, __fmul_rn(0.25f, m));         // q + 0.25*e, fp32 like ref
}

extern "C" void kernel_launch(void* const* d_in, const int* in_sizes, int n_in,
                              void* d_out, int out_size, void* d_ws, size_t ws_size,
                              hipStream_t stream) {
    const float* x = (const float*)d_in[0];   // cnt_emb [64,2048,80]
    const float* w = (const float*)d_in[1];   // embed_weight [1024,80]
    float* out = (float*)d_out;

    int n = in_sizes[0] / D;                  // 131072 rows

    double* acc = (double*)d_ws;
    float* en = (float*)((char*)d_ws + 64);
    float* ec = en + NE * D;

    hipMemsetAsync(d_ws, 0, 64, stream);
    vq_prep<<<(NE + 255) / 256, 256, 0, stream>>>(w, en, ec);
    vq_main<<<(n + 255) / 256, 256, 0, stream>>>(x, w, en, ec, out, acc, n);
    vq_fin_kernel<<<1, 1, 0, stream>>>(acc, out + (size_t)n * D, (double)n * D);
}